// Round 8
// baseline (169.536 us; speedup 1.0000x reference)
//
#include <hip/hip_runtime.h>

// ZBL pair potential + segment-sum into per-atom energies.
// Inputs (setup_inputs order):
//   d_in[0] Z            (4,)     float32
//   d_in[1] r            (E,)     float32   E = 6,400,000
//   d_in[2] per_atom_energy (N,1) float32   N = 100,000
//   d_in[3] atom_types   (N,)     int32
//   d_in[4] edge_index   (2,E)    int32
// Output: (N,1) float32 = segment_sum(edge_eng, edge_index[0]) + per_atom_energy
//
// R20: R19's table exposed that xcd-colocated P2 @ grid 240 (R15) is a net
// REGRESSION: P2 visible at 41.3-41.6us vs <40.6 (~35-37us) at grid 255.
// P2 is DS-pipe-bound (R13-R17 ladder: ds_add_f32 ~4.3 cyc/active-lane);
// losing 16 CUs costs ~6% of P2 while the L2-hit gain (FETCH 3x lower) is
// worth zero time. Fix: generic mapping, S2=85, grid 255. Keep R19's P1
// float2 table + float4 reduce + 8-deep loads + float4 init/flush.
// Substrate ladder (all measured): LDS conditional atomic 40us (floor ~37) <<
// branchless-LDS 143us << LLC atomics 260us. Grid 126 = 62us (CU-linear).
// Practical ceiling arithmetic: fills ~83 (harness) + P2 ~36 + P1 ~32 +
// reduce ~6 + pack ~1.5 ~= 159-163us total.

namespace {
constexpr float PZBL     = 0.23f;
constexpr float A0_INV   = 1.0f / 0.4685f;
constexpr float C1 = 0.02817f, C2 = 0.28022f, C3 = 0.50986f, C4 = 0.18175f;
constexpr float D1 = -0.20162f, D2 = -0.4029f, D3 = -0.94229f, D4 = -3.1998f;
constexpr float QQ       = 14.399645f * 0.5f;
constexpr float RMAX     = 6.0f;
constexpr float RMAX_INV = 1.0f / 6.0f;
constexpr int   TPW_MAX  = 6400;   // packed-type words in LDS (<=102400 atoms)
constexpr int   P1_BLOCK = 256;
constexpr int   P1_GRID  = 1536;   // 6 blocks/CU @ 25.6 KB LDS
// Phase-2 binning:
constexpr int   CHUNK2   = 33344;  // 130.25 KiB fp32 bins -> 3 chunks for 100K
constexpr int   BLOCK    = 1024;
// Single-pass fallback (R7-proven):
constexpr int   CHUNK1   = 25600;
constexpr int   S1_MAX   = 64;
}

// Pack atom_types (0..3) to 2 bits/atom: word w holds atoms 16w..16w+15.
__global__ void zbl_pack_types(const int* __restrict__ types,
                               unsigned* __restrict__ tpw,
                               int n_words, int n_atoms) {
    int w = blockIdx.x * blockDim.x + threadIdx.x;
    if (w >= n_words) return;
    unsigned v = 0;
    int base = w * 16;
    int m = min(16, n_atoms - base);
    for (int j = 0; j < m; ++j)
        v |= ((unsigned)types[base + j] & 3u) << (2 * j);
    tpw[w] = v;
}

// Branchless masked edge energy from LDS tables (result >= 0).
// s_zzx[tp] = { QQ*Zi*Zj , (Zi^p + Zj^p)/a0 } -> one ds_read_b64.
__device__ __forceinline__ float edge_eng_lds(float rk, int ia, int ib,
                                              const unsigned* s_tp,
                                              const float2* s_zzx) {
    unsigned ti = (s_tp[ia >> 4] >> ((ia & 15) * 2)) & 3u;
    unsigned tj = (s_tp[ib >> 4] >> ((ib & 15) * 2)) & 3u;
    int tp = (int)((ti << 2) | tj);
    float2 t = s_zzx[tp];
    float x = t.y * rk;
    float psi = C1 * __expf(D1 * x) + C2 * __expf(D2 * x)
              + C3 * __expf(D3 * x) + C4 * __expf(D4 * x);
    float eng = t.x * psi * __builtin_amdgcn_rcpf(rk);
    float rr = rk * RMAX_INV;
    // p=6 polynomial cutoff: 1 - 28 rr^6 + 48 rr^7 - 21 rr^8
    float rr2 = rr * rr;
    float rr3 = rr2 * rr;
    float rr6 = rr3 * rr3;
    float cutoff = 1.0f + rr6 * (-28.0f + rr * (48.0f - 21.0f * rr));
    return (rk < RMAX) ? cutoff * eng : 0.0f;
}

// Pack (dest, energy>=0) into 32 bits: dest<<15 | bf15 (8e+7m, RTN).
__device__ __forceinline__ unsigned pack_rec(int dest, float e) {
    unsigned b = __float_as_uint(e);            // sign bit is 0
    unsigned v = (b + 0x8000u) >> 16;           // round-to-nearest 15-bit float
    return ((unsigned)dest << 15) | (v & 0x7FFFu);
}

// Phase 1: stream edges, write 4-byte packed (dest|eng15) records.
// ~25.7 KB LDS -> 6 blocks/CU; grid-stride; 2 quads per iteration.
__global__ __launch_bounds__(P1_BLOCK) void zbl_energy_kernel(
    const float*    __restrict__ Z,
    const float*    __restrict__ r,
    const int*      __restrict__ ei0,
    const int*      __restrict__ ei1,
    const unsigned* __restrict__ tpw,
    unsigned*       __restrict__ rec,    // n_edges u32 records
    int n_tp_words, int n_oct, int n_edges) {
    __shared__ unsigned s_tp[TPW_MAX];   // 25.6 KB
    __shared__ float2   s_zzx[16];       // {QQ*Zi*Zj, (Zi^p+Zj^p)/a0}

    const int tid = threadIdx.x;
    for (int i = tid; i < n_tp_words; i += P1_BLOCK) s_tp[i] = tpw[i];
    if (tid < 16) {
        int ti = tid >> 2, tj = tid & 3;
        float zi = Z[ti], zj = Z[tj];
        s_zzx[tid] = make_float2(QQ * zi * zj,
                                 (powf(zi, PZBL) + powf(zj, PZBL)) * A0_INV);
    }
    __syncthreads();

    const float4* r4 = (const float4*)r;
    const int4*   a4 = (const int4*)ei0;
    const int4*   b4 = (const int4*)ei1;
    uint4*        rc4 = (uint4*)rec;
    const int stride = gridDim.x * P1_BLOCK;
    const int gtid = blockIdx.x * P1_BLOCK + tid;

    // One "oct" = 2 consecutive quads = 8 edges: 6 independent 16B loads.
    for (int o = gtid; o < n_oct; o += stride) {
        int qa = 2 * o, qb = 2 * o + 1;
        float4 rva = r4[qa], rvb = r4[qb];
        int4   ava = a4[qa], avb = a4[qb];
        int4   bva = b4[qa], bvb = b4[qb];
        uint4 wa, wb;
        wa.x = pack_rec(ava.x, edge_eng_lds(rva.x, ava.x, bva.x, s_tp, s_zzx));
        wa.y = pack_rec(ava.y, edge_eng_lds(rva.y, ava.y, bva.y, s_tp, s_zzx));
        wa.z = pack_rec(ava.z, edge_eng_lds(rva.z, ava.z, bva.z, s_tp, s_zzx));
        wa.w = pack_rec(ava.w, edge_eng_lds(rva.w, ava.w, bva.w, s_tp, s_zzx));
        wb.x = pack_rec(avb.x, edge_eng_lds(rvb.x, avb.x, bvb.x, s_tp, s_zzx));
        wb.y = pack_rec(avb.y, edge_eng_lds(rvb.y, avb.y, bvb.y, s_tp, s_zzx));
        wb.z = pack_rec(avb.z, edge_eng_lds(rvb.z, avb.z, bvb.z, s_tp, s_zzx));
        wb.w = pack_rec(avb.w, edge_eng_lds(rvb.w, avb.w, bvb.w, s_tp, s_zzx));
        rc4[qa] = wa;
        rc4[qb] = wb;
    }
    // Scalar tail (edges beyond the oct region), grid-strided.
    for (int e = 8 * n_oct + gtid; e < n_edges; e += stride) {
        int ia = ei0[e];
        rec[e] = pack_rec(ia, edge_eng_lds(r[e], ia, ei1[e], s_tp, s_zzx));
    }
}

// Phase 2: 8x uint4 record loads in flight, bounds test, conditional LDS
// atomic, flush. Grid MUST be ~full machine, 255 blocks (R13/R19: DS-pipe
// throughput is CU-linear; 240-grid xcd mode was -6% P2. No tail round.)
__global__ __launch_bounds__(BLOCK) void zbl_bin_kernel(
    const uint4* __restrict__ rec4,
    const unsigned* __restrict__ rec,
    float*       __restrict__ partials,   // [S*C][CHUNK2]
    int n_chunks, int u4_per_slice, int n_u4, int n_records) {
    __shared__ __align__(16) float bins[CHUNK2];  // 130.25 KiB
    {
        float4* b4 = (float4*)bins;
        const float4 z4 = make_float4(0.f, 0.f, 0.f, 0.f);
        for (int i = threadIdx.x; i < CHUNK2 / 4; i += BLOCK) b4[i] = z4;
    }
    __syncthreads();

    const int c = blockIdx.x % n_chunks;
    const int s = blockIdx.x / n_chunks;
    const unsigned base = (unsigned)c * CHUNK2;

    auto lane = [&](unsigned w) {
        unsigned d = (w >> 15) - base;
        unsigned v = w & 0x7FFFu;
        if (d < (unsigned)CHUNK2 && v != 0u)
            atomicAdd(&bins[d], __uint_as_float(v << 16));
    };

    const int q0 = s * u4_per_slice;
    const int q1 = min(n_u4, q0 + u4_per_slice);
    const uint4 dead = make_uint4(0, 0, 0, 0);  // v==0 -> skipped

    for (int q = q0 + threadIdx.x; q < q1; q += 8 * BLOCK) {
        uint4 p0 = rec4[q];
        uint4 p1 = (q + 1 * BLOCK < q1) ? rec4[q + 1 * BLOCK] : dead;
        uint4 p2 = (q + 2 * BLOCK < q1) ? rec4[q + 2 * BLOCK] : dead;
        uint4 p3 = (q + 3 * BLOCK < q1) ? rec4[q + 3 * BLOCK] : dead;
        uint4 p4 = (q + 4 * BLOCK < q1) ? rec4[q + 4 * BLOCK] : dead;
        uint4 p5 = (q + 5 * BLOCK < q1) ? rec4[q + 5 * BLOCK] : dead;
        uint4 p6 = (q + 6 * BLOCK < q1) ? rec4[q + 6 * BLOCK] : dead;
        uint4 p7 = (q + 7 * BLOCK < q1) ? rec4[q + 7 * BLOCK] : dead;
        lane(p0.x); lane(p0.y); lane(p0.z); lane(p0.w);
        lane(p1.x); lane(p1.y); lane(p1.z); lane(p1.w);
        lane(p2.x); lane(p2.y); lane(p2.z); lane(p2.w);
        lane(p3.x); lane(p3.y); lane(p3.z); lane(p3.w);
        lane(p4.x); lane(p4.y); lane(p4.z); lane(p4.w);
        lane(p5.x); lane(p5.y); lane(p5.z); lane(p5.w);
        lane(p6.x); lane(p6.y); lane(p6.z); lane(p6.w);
        lane(p7.x); lane(p7.y); lane(p7.z); lane(p7.w);
    }
    // Scalar record tail, handled once by the s==0 blocks (one per chunk).
    if (s == 0) {
        for (int e = 4 * n_u4 + threadIdx.x; e < n_records; e += BLOCK)
            lane(rec[e]);
    }
    __syncthreads();

    float4* dst = (float4*)(partials + (size_t)blockIdx.x * CHUNK2);
    const float4* src = (const float4*)bins;
    for (int i = threadIdx.x; i < CHUNK2 / 4; i += BLOCK) dst[i] = src[i];
}

// out[a] = pae[a] + sum over slices of partials[s*C + c][a - c*chunk].
// float4 path: 4 atoms/thread (chunk % 4 == 0 so a group never straddles c).
__global__ void zbl_reduce_out(const float* __restrict__ pae,
                               const float* __restrict__ partials,
                               float* __restrict__ out,
                               int n_atoms, int n_chunks, int n_slices,
                               int chunk) {
    int g = blockIdx.x * blockDim.x + threadIdx.x;
    int a = g * 4;
    if (a + 3 < n_atoms && (chunk & 3) == 0) {
        int c = a / chunk;
        int i = a - c * chunk;
        const float4* p =
            (const float4*)(partials + (size_t)c * chunk + i);
        const size_t stride4 = ((size_t)n_chunks * chunk) >> 2;
        float4 s0 = make_float4(0.f, 0.f, 0.f, 0.f);
        float4 s1 = make_float4(0.f, 0.f, 0.f, 0.f);
        int s = 0;
        for (; s + 2 <= n_slices; s += 2) {
            float4 v0 = p[(size_t)(s + 0) * stride4];
            float4 v1 = p[(size_t)(s + 1) * stride4];
            s0.x += v0.x; s0.y += v0.y; s0.z += v0.z; s0.w += v0.w;
            s1.x += v1.x; s1.y += v1.y; s1.z += v1.z; s1.w += v1.w;
        }
        for (; s < n_slices; ++s) {
            float4 v0 = p[(size_t)s * stride4];
            s0.x += v0.x; s0.y += v0.y; s0.z += v0.z; s0.w += v0.w;
        }
        float4 pv = *(const float4*)(pae + a);
        float4 o;
        o.x = pv.x + s0.x + s1.x;
        o.y = pv.y + s0.y + s1.y;
        o.z = pv.z + s0.z + s1.z;
        o.w = pv.w + s0.w + s1.w;
        *(float4*)(out + a) = o;
    } else {
        for (int k = 0; k < 4; ++k) {
            int aa = a + k;
            if (aa >= n_atoms) return;
            int c = aa / chunk;
            int i = aa - c * chunk;
            const float* p = partials + (size_t)c * chunk + i;
            const size_t stride = (size_t)n_chunks * chunk;
            float acc = 0.0f;
            for (int s = 0; s < n_slices; ++s) acc += p[(size_t)s * stride];
            out[aa] = pae[aa] + acc;
        }
    }
}

// ---------- single-pass fallback (R7-proven) -------------------------------
__global__ __launch_bounds__(BLOCK) void zbl_chunk_kernel(
    const float*    __restrict__ Z,
    const float*    __restrict__ r,
    const int*      __restrict__ ei0,
    const int*      __restrict__ ei1,
    const unsigned* __restrict__ tpw,
    float*          __restrict__ partials,
    int n_chunks, int n_tp_words, int quads_per_slice,
    int n_quads, int n_edges) {
    __shared__ float    bins[CHUNK1];
    __shared__ unsigned s_tp[TPW_MAX];
    __shared__ float2   s_zzx[16];
    const int tid = threadIdx.x;
    for (int i = tid; i < n_tp_words; i += BLOCK) s_tp[i] = tpw[i];
    if (tid < 16) {
        int ti = tid >> 2, tj = tid & 3;
        float zi = Z[ti], zj = Z[tj];
        s_zzx[tid] = make_float2(QQ * zi * zj,
                                 (powf(zi, PZBL) + powf(zj, PZBL)) * A0_INV);
    }
    for (int i = tid; i < CHUNK1; i += BLOCK) bins[i] = 0.0f;
    __syncthreads();
    const int c = blockIdx.x % n_chunks;
    const int s = blockIdx.x / n_chunks;
    const int base = c * CHUNK1;
    const int q0 = s * quads_per_slice;
    const int q1 = min(n_quads, q0 + quads_per_slice);
    for (int q = q0 + tid; q < q1; q += BLOCK) {
        int4 av = ((const int4*)ei0)[q];
        unsigned d0 = (unsigned)(av.x - base);
        unsigned d1 = (unsigned)(av.y - base);
        unsigned d2 = (unsigned)(av.z - base);
        unsigned d3 = (unsigned)(av.w - base);
        bool m0 = d0 < (unsigned)CHUNK1, m1 = d1 < (unsigned)CHUNK1;
        bool m2 = d2 < (unsigned)CHUNK1, m3 = d3 < (unsigned)CHUNK1;
        if (!(m0 | m1 | m2 | m3)) continue;
        float4 rv = ((const float4*)r)[q];
        int4   bv = ((const int4*)ei1)[q];
        if (m0) { float e = edge_eng_lds(rv.x, av.x, bv.x, s_tp, s_zzx);
                  if (e != 0.0f) atomicAdd(&bins[d0], e); }
        if (m1) { float e = edge_eng_lds(rv.y, av.y, bv.y, s_tp, s_zzx);
                  if (e != 0.0f) atomicAdd(&bins[d1], e); }
        if (m2) { float e = edge_eng_lds(rv.z, av.z, bv.z, s_tp, s_zzx);
                  if (e != 0.0f) atomicAdd(&bins[d2], e); }
        if (m3) { float e = edge_eng_lds(rv.w, av.w, bv.w, s_tp, s_zzx);
                  if (e != 0.0f) atomicAdd(&bins[d3], e); }
    }
    if (s == 0) {
        for (int e = 4 * n_quads + tid; e < n_edges; e += BLOCK) {
            int ia = ei0[e];
            unsigned d = (unsigned)(ia - base);
            if (d < (unsigned)CHUNK1) {
                float e2 = edge_eng_lds(r[e], ia, ei1[e], s_tp, s_zzx);
                if (e2 != 0.0f) atomicAdd(&bins[d], e2);
            }
        }
    }
    __syncthreads();
    float* dst = partials + (size_t)blockIdx.x * CHUNK1;
    for (int i = tid; i < CHUNK1; i += BLOCK) dst[i] = bins[i];
}

// ---------- last-resort fallback: device-scope atomics into out ------------
__global__ void zbl_init_out(const float* __restrict__ pae,
                             float* __restrict__ out, int n) {
    int i = blockIdx.x * blockDim.x + threadIdx.x;
    if (i < n) out[i] = pae[i];
}

__global__ __launch_bounds__(256) void zbl_edge_fallback(
    const float* __restrict__ Z,
    const float* __restrict__ r,
    const int*   __restrict__ ei0,
    const int*   __restrict__ ei1,
    const int*   __restrict__ types,
    float*       __restrict__ out,
    int n_edges) {
    __shared__ float s_z[4];
    __shared__ float s_zp[4];
    if (threadIdx.x < 4) {
        float z = Z[threadIdx.x];
        s_z[threadIdx.x]  = z;
        s_zp[threadIdx.x] = powf(z, PZBL);
    }
    __syncthreads();
    int e = blockIdx.x * blockDim.x + threadIdx.x;
    if (e >= n_edges) return;
    float rk = r[e];
    if (rk >= RMAX) return;
    int ia = ei0[e], ib = ei1[e];
    int ti = types[ia], tj = types[ib];
    float x = (s_zp[ti] + s_zp[tj]) * rk * A0_INV;
    float psi = C1 * __expf(D1 * x) + C2 * __expf(D2 * x)
              + C3 * __expf(D3 * x) + C4 * __expf(D4 * x);
    float eng = QQ * s_z[ti] * s_z[tj] * psi / rk;
    float rr = rk * RMAX_INV;
    float rr2 = rr * rr, rr3 = rr2 * rr, rr6 = rr3 * rr3;
    float cutoff = 1.0f + rr6 * (-28.0f + rr * (48.0f - 21.0f * rr));
    unsafeAtomicAdd(&out[ia], cutoff * eng);
}

extern "C" void kernel_launch(void* const* d_in, const int* in_sizes, int n_in,
                              void* d_out, int out_size, void* d_ws, size_t ws_size,
                              hipStream_t stream) {
    const float* Z     = (const float*)d_in[0];
    const float* r     = (const float*)d_in[1];
    const float* pae   = (const float*)d_in[2];
    const int*   types = (const int*)d_in[3];
    const int*   ei    = (const int*)d_in[4];

    const int n_edges = in_sizes[1];
    const int n_atoms = in_sizes[2];

    float* out = (float*)d_out;

    const int n_tp_words = (n_atoms + 15) / 16;
    const int n_quads    = (n_edges & 3) ? 0 : (n_edges >> 2);

    const size_t tp_bytes  = ((size_t)n_tp_words * 4 + 15) & ~(size_t)15;
    const size_t rec_bytes = ((size_t)n_edges * 4 + 15) & ~(size_t)15;

    // ---- two-phase sizing: grid nc2*S2 must be <= 256 (no tail round),
    //      and dest must fit 17 bits. P2 needs the FULL 255-block grid. ----
    const int nc2 = (n_atoms + CHUNK2 - 1) / CHUNK2;   // 3 for N=100K
    int S2 = (nc2 > 0) ? (256 / nc2) : 1;              // 85 for nc2=3
    while (S2 > 4 &&
           tp_bytes + rec_bytes +
           (size_t)nc2 * S2 * CHUNK2 * sizeof(float) > ws_size) {
        --S2;
    }
    const bool two_phase =
        n_tp_words <= TPW_MAX && n_atoms <= (1 << 17) && S2 >= 4 &&
        n_quads > 0 &&
        tp_bytes + rec_bytes + (size_t)nc2 * S2 * CHUNK2 * sizeof(float)
            <= ws_size;

    // ---- single-phase sizing (fallback) ----
    const int nc1 = (n_atoms + CHUNK1 - 1) / CHUNK1;
    const bool one_phase =
        n_tp_words <= TPW_MAX &&
        tp_bytes + (size_t)nc1 * S1_MAX * CHUNK1 * sizeof(float) <= ws_size;

    if (two_phase) {
        unsigned* tpw = (unsigned*)d_ws;
        unsigned* rec = (unsigned*)((char*)d_ws + tp_bytes);
        float* partials = (float*)((char*)d_ws + tp_bytes + rec_bytes);

        zbl_pack_types<<<(n_tp_words + 255) / 256, 256, 0, stream>>>(
            types, tpw, n_tp_words, n_atoms);

        const int n_oct = n_quads >> 1;
        zbl_energy_kernel<<<P1_GRID, P1_BLOCK, 0, stream>>>(
            Z, r, ei, ei + n_edges, tpw, rec, n_tp_words, n_oct, n_edges);

        const int n_u4 = n_edges >> 2;
        const int u4_per_slice = (n_u4 + S2 - 1) / S2;
        zbl_bin_kernel<<<nc2 * S2, BLOCK, 0, stream>>>(
            (const uint4*)rec, rec, partials, nc2, u4_per_slice, n_u4, n_edges);

        const int n_groups = (n_atoms + 3) / 4;
        zbl_reduce_out<<<(n_groups + 255) / 256, 256, 0, stream>>>(
            pae, partials, out, n_atoms, nc2, S2, CHUNK2);
    } else if (one_phase) {
        unsigned* tpw = (unsigned*)d_ws;
        float* partials = (float*)((char*)d_ws + tp_bytes);

        zbl_pack_types<<<(n_tp_words + 255) / 256, 256, 0, stream>>>(
            types, tpw, n_tp_words, n_atoms);

        const int quads_per_slice = (n_quads + S1_MAX - 1) / S1_MAX;
        zbl_chunk_kernel<<<nc1 * S1_MAX, BLOCK, 0, stream>>>(
            Z, r, ei, ei + n_edges, tpw, partials,
            nc1, n_tp_words, quads_per_slice, n_quads, n_edges);

        const int n_groups = (n_atoms + 3) / 4;
        zbl_reduce_out<<<(n_groups + 255) / 256, 256, 0, stream>>>(
            pae, partials, out, n_atoms, nc1, S1_MAX, CHUNK1);
    } else {
        zbl_init_out<<<(n_atoms + 255) / 256, 256, 0, stream>>>(pae, out, n_atoms);
        zbl_edge_fallback<<<(n_edges + 255) / 256, 256, 0, stream>>>(
            Z, r, ei, ei + n_edges, types, out, n_edges);
    }
}

// Round 9
// 164.055 us; speedup vs baseline: 1.0334x; 1.0334x over previous
//
#include <hip/hip_runtime.h>

// ZBL pair potential + segment-sum into per-atom energies.
// Inputs (setup_inputs order):
//   d_in[0] Z            (4,)     float32
//   d_in[1] r            (E,)     float32   E = 6,400,000
//   d_in[2] per_atom_energy (N,1) float32   N = 100,000
//   d_in[3] atom_types   (N,)     int32
//   d_in[4] edge_index   (2,E)    int32
// Output: (N,1) float32 = segment_sum(edge_eng, edge_index[0]) + per_atom_energy
//
// R21: FINAL REVERT to the best-measured configuration (R12 source, 163.9us).
// Session ledger (R13-R20, all measured):
//   - P2 grid 126 (R13): 62.6us -> P2 is per-CU DS-pipe-bound, CU-linear.
//   - 8-deep loads (R14): null. XCD-colocate (R15): FETCH/3 but time null ->
//     fetch not critical. Branchless ds_add (R16): 143us -> cost is per
//     ACTIVE LANE (~4.3cyc), not per-wave exec dance. LLC atomics (R17):
//     260us -> 12x worse. xcd-240 grid (R19): -6% P2. Micro-polish
//     (float2 table / float4 reduce, R19-R20): within noise, net drift +5us.
// Ceiling arithmetic: fills ~83 (harness poison, fixed) + P2 ~38-40 (LDS
// atomic floor 5.25M adds/255CU*4.3cyc ~ 37us) + P1 ~30-34 + reduce ~6 +
// pack ~1.5 => ~160 +/- 5us. R12 structure sits on that floor.

namespace {
constexpr float PZBL     = 0.23f;
constexpr float A0_INV   = 1.0f / 0.4685f;
constexpr float C1 = 0.02817f, C2 = 0.28022f, C3 = 0.50986f, C4 = 0.18175f;
constexpr float D1 = -0.20162f, D2 = -0.4029f, D3 = -0.94229f, D4 = -3.1998f;
constexpr float QQ       = 14.399645f * 0.5f;
constexpr float RMAX     = 6.0f;
constexpr float RMAX_INV = 1.0f / 6.0f;
constexpr int   TPW_MAX  = 6400;   // packed-type words in LDS (<=102400 atoms)
constexpr int   P1_BLOCK = 256;
constexpr int   P1_GRID  = 1536;   // 6 blocks/CU @ 25.6 KB LDS
// Phase-2 binning:
constexpr int   CHUNK2   = 33344;  // 130.25 KiB fp32 bins -> 3 chunks for 100K
constexpr int   BLOCK    = 1024;
// Single-pass fallback (R7-proven):
constexpr int   CHUNK1   = 25600;
constexpr int   S1_MAX   = 64;
}

// Pack atom_types (0..3) to 2 bits/atom: word w holds atoms 16w..16w+15.
__global__ void zbl_pack_types(const int* __restrict__ types,
                               unsigned* __restrict__ tpw,
                               int n_words, int n_atoms) {
    int w = blockIdx.x * blockDim.x + threadIdx.x;
    if (w >= n_words) return;
    unsigned v = 0;
    int base = w * 16;
    int m = min(16, n_atoms - base);
    for (int j = 0; j < m; ++j)
        v |= ((unsigned)types[base + j] & 3u) << (2 * j);
    tpw[w] = v;
}

// Branchless masked edge energy from LDS tables (result >= 0).
__device__ __forceinline__ float edge_eng_lds(float rk, int ia, int ib,
                                              const unsigned* s_tp,
                                              const float* s_zz,
                                              const float* s_zx) {
    unsigned ti = (s_tp[ia >> 4] >> ((ia & 15) * 2)) & 3u;
    unsigned tj = (s_tp[ib >> 4] >> ((ib & 15) * 2)) & 3u;
    int tp = (int)((ti << 2) | tj);
    float x = s_zx[tp] * rk;
    float psi = C1 * __expf(D1 * x) + C2 * __expf(D2 * x)
              + C3 * __expf(D3 * x) + C4 * __expf(D4 * x);
    float eng = s_zz[tp] * psi * __builtin_amdgcn_rcpf(rk);
    float rr = rk * RMAX_INV;
    // p=6 polynomial cutoff: 1 - 28 rr^6 + 48 rr^7 - 21 rr^8
    float rr2 = rr * rr;
    float rr3 = rr2 * rr;
    float rr6 = rr3 * rr3;
    float cutoff = 1.0f + rr6 * (-28.0f + rr * (48.0f - 21.0f * rr));
    return (rk < RMAX) ? cutoff * eng : 0.0f;
}

// Pack (dest, energy>=0) into 32 bits: dest<<15 | bf15 (8e+7m, RTN).
__device__ __forceinline__ unsigned pack_rec(int dest, float e) {
    unsigned b = __float_as_uint(e);            // sign bit is 0
    unsigned v = (b + 0x8000u) >> 16;           // round-to-nearest 15-bit float
    return ((unsigned)dest << 15) | (v & 0x7FFFu);
}

// Phase 1: stream edges, write 4-byte packed (dest|eng15) records.
// ~25.7 KB LDS -> 6 blocks/CU; grid-stride; 2 quads per iteration.
__global__ __launch_bounds__(P1_BLOCK) void zbl_energy_kernel(
    const float*    __restrict__ Z,
    const float*    __restrict__ r,
    const int*      __restrict__ ei0,
    const int*      __restrict__ ei1,
    const unsigned* __restrict__ tpw,
    unsigned*       __restrict__ rec,    // n_edges u32 records
    int n_tp_words, int n_oct, int n_edges) {
    __shared__ unsigned s_tp[TPW_MAX];   // 25.6 KB
    __shared__ float    s_zz[16];        // QQ * Zi * Zj
    __shared__ float    s_zx[16];        // (Zi^p + Zj^p) / a0

    const int tid = threadIdx.x;
    for (int i = tid; i < n_tp_words; i += P1_BLOCK) s_tp[i] = tpw[i];
    if (tid < 16) {
        int ti = tid >> 2, tj = tid & 3;
        float zi = Z[ti], zj = Z[tj];
        s_zz[tid] = QQ * zi * zj;
        s_zx[tid] = (powf(zi, PZBL) + powf(zj, PZBL)) * A0_INV;
    }
    __syncthreads();

    const float4* r4 = (const float4*)r;
    const int4*   a4 = (const int4*)ei0;
    const int4*   b4 = (const int4*)ei1;
    uint4*        rc4 = (uint4*)rec;
    const int stride = gridDim.x * P1_BLOCK;
    const int gtid = blockIdx.x * P1_BLOCK + tid;

    // One "oct" = 2 consecutive quads = 8 edges: 6 independent 16B loads.
    for (int o = gtid; o < n_oct; o += stride) {
        int qa = 2 * o, qb = 2 * o + 1;
        float4 rva = r4[qa], rvb = r4[qb];
        int4   ava = a4[qa], avb = a4[qb];
        int4   bva = b4[qa], bvb = b4[qb];
        uint4 wa, wb;
        wa.x = pack_rec(ava.x, edge_eng_lds(rva.x, ava.x, bva.x, s_tp, s_zz, s_zx));
        wa.y = pack_rec(ava.y, edge_eng_lds(rva.y, ava.y, bva.y, s_tp, s_zz, s_zx));
        wa.z = pack_rec(ava.z, edge_eng_lds(rva.z, ava.z, bva.z, s_tp, s_zz, s_zx));
        wa.w = pack_rec(ava.w, edge_eng_lds(rva.w, ava.w, bva.w, s_tp, s_zz, s_zx));
        wb.x = pack_rec(avb.x, edge_eng_lds(rvb.x, avb.x, bvb.x, s_tp, s_zz, s_zx));
        wb.y = pack_rec(avb.y, edge_eng_lds(rvb.y, avb.y, bvb.y, s_tp, s_zz, s_zx));
        wb.z = pack_rec(avb.z, edge_eng_lds(rvb.z, avb.z, bvb.z, s_tp, s_zz, s_zx));
        wb.w = pack_rec(avb.w, edge_eng_lds(rvb.w, avb.w, bvb.w, s_tp, s_zz, s_zx));
        rc4[qa] = wa;
        rc4[qb] = wb;
    }
    // Scalar tail (edges beyond the oct region), grid-strided.
    for (int e = 8 * n_oct + gtid; e < n_edges; e += stride) {
        int ia = ei0[e];
        rec[e] = pack_rec(ia, edge_eng_lds(r[e], ia, ei1[e], s_tp, s_zz, s_zx));
    }
}

// Phase 2: 4x uint4 record loads in flight, bounds test, ds_add, flush.
// Grid MUST be <= 256 blocks (1 block/CU at 130 KB LDS, no tail round).
__global__ __launch_bounds__(BLOCK) void zbl_bin_kernel(
    const uint4* __restrict__ rec4,
    const unsigned* __restrict__ rec,
    float*       __restrict__ partials,   // [S*C][CHUNK2]
    int n_chunks, int u4_per_slice, int n_u4, int n_records) {
    __shared__ float bins[CHUNK2];        // 130.25 KiB
    for (int i = threadIdx.x; i < CHUNK2; i += BLOCK) bins[i] = 0.0f;
    __syncthreads();

    const int c = blockIdx.x % n_chunks;
    const int s = blockIdx.x / n_chunks;
    const unsigned base = (unsigned)c * CHUNK2;

    auto lane = [&](unsigned w) {
        unsigned d = (w >> 15) - base;
        unsigned v = w & 0x7FFFu;
        if (d < (unsigned)CHUNK2 && v != 0u)
            atomicAdd(&bins[d], __uint_as_float(v << 16));
    };

    const int q0 = s * u4_per_slice;
    const int q1 = min(n_u4, q0 + u4_per_slice);
    const uint4 dead = make_uint4(0, 0, 0, 0);  // v==0 -> skipped

    for (int q = q0 + threadIdx.x; q < q1; q += 4 * BLOCK) {
        uint4 p0 = rec4[q];
        uint4 p1 = (q + 1 * BLOCK < q1) ? rec4[q + 1 * BLOCK] : dead;
        uint4 p2 = (q + 2 * BLOCK < q1) ? rec4[q + 2 * BLOCK] : dead;
        uint4 p3 = (q + 3 * BLOCK < q1) ? rec4[q + 3 * BLOCK] : dead;
        lane(p0.x); lane(p0.y); lane(p0.z); lane(p0.w);
        lane(p1.x); lane(p1.y); lane(p1.z); lane(p1.w);
        lane(p2.x); lane(p2.y); lane(p2.z); lane(p2.w);
        lane(p3.x); lane(p3.y); lane(p3.z); lane(p3.w);
    }
    // Scalar record tail, handled once by the s==0 blocks.
    if (s == 0) {
        for (int e = 4 * n_u4 + threadIdx.x; e < n_records; e += BLOCK)
            lane(rec[e]);
    }
    __syncthreads();

    float* dst = partials + (size_t)blockIdx.x * CHUNK2;
    for (int i = threadIdx.x; i < CHUNK2; i += BLOCK) dst[i] = bins[i];
}

// out[a] = pae[a] + sum over slices of partials[s*C + c][a - c*chunk].
__global__ void zbl_reduce_out(const float* __restrict__ pae,
                               const float* __restrict__ partials,
                               float* __restrict__ out,
                               int n_atoms, int n_chunks, int n_slices,
                               int chunk) {
    int a = blockIdx.x * blockDim.x + threadIdx.x;
    if (a >= n_atoms) return;
    int c = a / chunk;
    int i = a - c * chunk;
    const float* p = partials + (size_t)c * chunk + i;
    const size_t stride = (size_t)n_chunks * chunk;
    float s0 = 0.0f, s1 = 0.0f, s2 = 0.0f, s3 = 0.0f;
    int s = 0;
    for (; s + 4 <= n_slices; s += 4) {
        s0 += p[(size_t)(s + 0) * stride];
        s1 += p[(size_t)(s + 1) * stride];
        s2 += p[(size_t)(s + 2) * stride];
        s3 += p[(size_t)(s + 3) * stride];
    }
    for (; s < n_slices; ++s) s0 += p[(size_t)s * stride];
    out[a] = pae[a] + ((s0 + s1) + (s2 + s3));
}

// ---------- single-pass fallback (R7-proven) -------------------------------
__global__ __launch_bounds__(BLOCK) void zbl_chunk_kernel(
    const float*    __restrict__ Z,
    const float*    __restrict__ r,
    const int*      __restrict__ ei0,
    const int*      __restrict__ ei1,
    const unsigned* __restrict__ tpw,
    float*          __restrict__ partials,
    int n_chunks, int n_tp_words, int quads_per_slice,
    int n_quads, int n_edges) {
    __shared__ float    bins[CHUNK1];
    __shared__ unsigned s_tp[TPW_MAX];
    __shared__ float    s_zz[16];
    __shared__ float    s_zx[16];
    const int tid = threadIdx.x;
    for (int i = tid; i < n_tp_words; i += BLOCK) s_tp[i] = tpw[i];
    if (tid < 16) {
        int ti = tid >> 2, tj = tid & 3;
        float zi = Z[ti], zj = Z[tj];
        s_zz[tid] = QQ * zi * zj;
        s_zx[tid] = (powf(zi, PZBL) + powf(zj, PZBL)) * A0_INV;
    }
    for (int i = tid; i < CHUNK1; i += BLOCK) bins[i] = 0.0f;
    __syncthreads();
    const int c = blockIdx.x % n_chunks;
    const int s = blockIdx.x / n_chunks;
    const int base = c * CHUNK1;
    const int q0 = s * quads_per_slice;
    const int q1 = min(n_quads, q0 + quads_per_slice);
    for (int q = q0 + tid; q < q1; q += BLOCK) {
        int4 av = ((const int4*)ei0)[q];
        unsigned d0 = (unsigned)(av.x - base);
        unsigned d1 = (unsigned)(av.y - base);
        unsigned d2 = (unsigned)(av.z - base);
        unsigned d3 = (unsigned)(av.w - base);
        bool m0 = d0 < (unsigned)CHUNK1, m1 = d1 < (unsigned)CHUNK1;
        bool m2 = d2 < (unsigned)CHUNK1, m3 = d3 < (unsigned)CHUNK1;
        if (!(m0 | m1 | m2 | m3)) continue;
        float4 rv = ((const float4*)r)[q];
        int4   bv = ((const int4*)ei1)[q];
        if (m0) { float e = edge_eng_lds(rv.x, av.x, bv.x, s_tp, s_zz, s_zx);
                  if (e != 0.0f) atomicAdd(&bins[d0], e); }
        if (m1) { float e = edge_eng_lds(rv.y, av.y, bv.y, s_tp, s_zz, s_zx);
                  if (e != 0.0f) atomicAdd(&bins[d1], e); }
        if (m2) { float e = edge_eng_lds(rv.z, av.z, bv.z, s_tp, s_zz, s_zx);
                  if (e != 0.0f) atomicAdd(&bins[d2], e); }
        if (m3) { float e = edge_eng_lds(rv.w, av.w, bv.w, s_tp, s_zz, s_zx);
                  if (e != 0.0f) atomicAdd(&bins[d3], e); }
    }
    if (s == 0) {
        for (int e = 4 * n_quads + tid; e < n_edges; e += BLOCK) {
            int ia = ei0[e];
            unsigned d = (unsigned)(ia - base);
            if (d < (unsigned)CHUNK1) {
                float e2 = edge_eng_lds(r[e], ia, ei1[e], s_tp, s_zz, s_zx);
                if (e2 != 0.0f) atomicAdd(&bins[d], e2);
            }
        }
    }
    __syncthreads();
    float* dst = partials + (size_t)blockIdx.x * CHUNK1;
    for (int i = tid; i < CHUNK1; i += BLOCK) dst[i] = bins[i];
}

// ---------- last-resort fallback: device-scope atomics into out ------------
__global__ void zbl_init_out(const float* __restrict__ pae,
                             float* __restrict__ out, int n) {
    int i = blockIdx.x * blockDim.x + threadIdx.x;
    if (i < n) out[i] = pae[i];
}

__global__ __launch_bounds__(256) void zbl_edge_fallback(
    const float* __restrict__ Z,
    const float* __restrict__ r,
    const int*   __restrict__ ei0,
    const int*   __restrict__ ei1,
    const int*   __restrict__ types,
    float*       __restrict__ out,
    int n_edges) {
    __shared__ float s_z[4];
    __shared__ float s_zp[4];
    if (threadIdx.x < 4) {
        float z = Z[threadIdx.x];
        s_z[threadIdx.x]  = z;
        s_zp[threadIdx.x] = powf(z, PZBL);
    }
    __syncthreads();
    int e = blockIdx.x * blockDim.x + threadIdx.x;
    if (e >= n_edges) return;
    float rk = r[e];
    if (rk >= RMAX) return;
    int ia = ei0[e], ib = ei1[e];
    int ti = types[ia], tj = types[ib];
    float x = (s_zp[ti] + s_zp[tj]) * rk * A0_INV;
    float psi = C1 * __expf(D1 * x) + C2 * __expf(D2 * x)
              + C3 * __expf(D3 * x) + C4 * __expf(D4 * x);
    float eng = QQ * s_z[ti] * s_z[tj] * psi / rk;
    float rr = rk * RMAX_INV;
    float rr2 = rr * rr, rr3 = rr2 * rr, rr6 = rr3 * rr3;
    float cutoff = 1.0f + rr6 * (-28.0f + rr * (48.0f - 21.0f * rr));
    unsafeAtomicAdd(&out[ia], cutoff * eng);
}

extern "C" void kernel_launch(void* const* d_in, const int* in_sizes, int n_in,
                              void* d_out, int out_size, void* d_ws, size_t ws_size,
                              hipStream_t stream) {
    const float* Z     = (const float*)d_in[0];
    const float* r     = (const float*)d_in[1];
    const float* pae   = (const float*)d_in[2];
    const int*   types = (const int*)d_in[3];
    const int*   ei    = (const int*)d_in[4];

    const int n_edges = in_sizes[1];
    const int n_atoms = in_sizes[2];

    float* out = (float*)d_out;

    const int n_tp_words = (n_atoms + 15) / 16;
    const int n_quads    = (n_edges & 3) ? 0 : (n_edges >> 2);

    const size_t tp_bytes  = ((size_t)n_tp_words * 4 + 15) & ~(size_t)15;
    const size_t rec_bytes = ((size_t)n_edges * 4 + 15) & ~(size_t)15;

    // ---- two-phase sizing: grid nc2*S2 must be <= 256 (no tail round),
    //      and dest must fit 17 bits ----
    const int nc2 = (n_atoms + CHUNK2 - 1) / CHUNK2;   // 3 for N=100K
    int S2 = (nc2 > 0) ? (256 / nc2) : 1;              // 85 for nc2=3
    while (S2 > 4 &&
           tp_bytes + rec_bytes +
           (size_t)nc2 * S2 * CHUNK2 * sizeof(float) > ws_size) {
        --S2;
    }
    const bool two_phase =
        n_tp_words <= TPW_MAX && n_atoms <= (1 << 17) && S2 >= 4 &&
        n_quads > 0 &&
        tp_bytes + rec_bytes + (size_t)nc2 * S2 * CHUNK2 * sizeof(float)
            <= ws_size;

    // ---- single-phase sizing (fallback) ----
    const int nc1 = (n_atoms + CHUNK1 - 1) / CHUNK1;
    const bool one_phase =
        n_tp_words <= TPW_MAX &&
        tp_bytes + (size_t)nc1 * S1_MAX * CHUNK1 * sizeof(float) <= ws_size;

    if (two_phase) {
        unsigned* tpw = (unsigned*)d_ws;
        unsigned* rec = (unsigned*)((char*)d_ws + tp_bytes);
        float* partials = (float*)((char*)d_ws + tp_bytes + rec_bytes);

        zbl_pack_types<<<(n_tp_words + 255) / 256, 256, 0, stream>>>(
            types, tpw, n_tp_words, n_atoms);

        const int n_oct = n_quads >> 1;
        zbl_energy_kernel<<<P1_GRID, P1_BLOCK, 0, stream>>>(
            Z, r, ei, ei + n_edges, tpw, rec, n_tp_words, n_oct, n_edges);

        const int n_u4 = n_edges >> 2;
        const int u4_per_slice = (n_u4 + S2 - 1) / S2;
        zbl_bin_kernel<<<nc2 * S2, BLOCK, 0, stream>>>(
            (const uint4*)rec, rec, partials, nc2, u4_per_slice, n_u4, n_edges);

        zbl_reduce_out<<<(n_atoms + 255) / 256, 256, 0, stream>>>(
            pae, partials, out, n_atoms, nc2, S2, CHUNK2);
    } else if (one_phase) {
        unsigned* tpw = (unsigned*)d_ws;
        float* partials = (float*)((char*)d_ws + tp_bytes);

        zbl_pack_types<<<(n_tp_words + 255) / 256, 256, 0, stream>>>(
            types, tpw, n_tp_words, n_atoms);

        const int quads_per_slice = (n_quads + S1_MAX - 1) / S1_MAX;
        zbl_chunk_kernel<<<nc1 * S1_MAX, BLOCK, 0, stream>>>(
            Z, r, ei, ei + n_edges, tpw, partials,
            nc1, n_tp_words, quads_per_slice, n_quads, n_edges);

        zbl_reduce_out<<<(n_atoms + 255) / 256, 256, 0, stream>>>(
            pae, partials, out, n_atoms, nc1, S1_MAX, CHUNK1);
    } else {
        zbl_init_out<<<(n_atoms + 255) / 256, 256, 0, stream>>>(pae, out, n_atoms);
        zbl_edge_fallback<<<(n_edges + 255) / 256, 256, 0, stream>>>(
            Z, r, ei, ei + n_edges, types, out, n_edges);
    }
}